// Round 2
// baseline (115.536 us; speedup 1.0000x reference)
//
#include <hip/hip_runtime.h>
#include <cmath>

// pa_lif: T=8, tau=0.25, thresh=0.5. Per-column recurrence (absmax 0.0 in R2):
//   w[i]   = 0.25*x[i] + 0.75*w[i-1]                      (W_CONST @ x as IIR)
//   p1[i]  = sigmoid(0.5 - 0.5*(0.25*x[i] + w[i]))
//   pre[i] = 0.25*(x[i] + S[i]) - 0.5 ;  out[i] = pre[i] > 0
//   S[i+1] = 0.25*p1[i]*(S[i] + x[i]) ;  S[0] = 0
//
// R4 restructure (fp64-refine was a per-WAVE tax): refine rate ~4%/thread
// => P(wave has a refining lane) ~= 1 - 0.96^64 ~= 93%, so nearly every
// wave executed the ~1200-instr fp64 exp() body (~19 us of VALU, equal to
// the ~21 us memory floor). Two-pass compaction:
//   pass1 (fast): fp32 path only, unconditional NT stores, wave-aggregated
//                 append of boundary tids to d_ws (1 atomicAdd per wave)
//   pass2 (tiny): fixed grid, grid-strides over the runtime count, fp64
//                 recompute of ~21K boundary threads only, stores last
// Cross-pass determinism: stream ordering + kernel-boundary release makes
// the pass2 overwrite of boundary outputs deterministic on every replay.
// Counter zeroed per replay via 16B hipMemsetAsync (stream-ordered,
// graph-capturable -- the harness's own reset uses the same mechanism).
// STEP32/STEP64 math unchanged bit-for-bit from the verified R2/R3 kernels;
// the refined set (mn < 5e-5) is identical.
//
// Fast sigmoid error analysis (R3, verified absmax 0.0): __expf + v_rcp give
// |pre| error <~1e-6; 50x margin under the 5e-5 refine threshold, and
// boundary lanes get exact fp64 regardless.

#define TT 8
#define REFINE_THRESH 5e-5f

// native vector type: __builtin_nontemporal_store requires a real vector,
// not HIP's float4 class
typedef float vfloat4 __attribute__((ext_vector_type(4)));

// one fast fp32 recurrence step for a single column (tracks min |pre| in `mn`)
#define STEP32(xik, w, S, o)                                  \
    {                                                         \
        float xk_ = (xik);                                    \
        w = fmaf(0.75f, w, 0.25f * xk_);                      \
        float arg_ = fmaf(-0.5f, fmaf(0.25f, xk_, w), 0.5f);  \
        float t_ = __expf(-arg_);                             \
        float p1_ = __builtin_amdgcn_rcpf(1.0f + t_);         \
        float sx_ = S + xk_;                                  \
        float pre_ = fmaf(0.25f, sx_, -0.5f);                 \
        o = (pre_ > 0.0f) ? 1.0f : 0.0f;                      \
        float a_ = fabsf(pre_);                               \
        mn = (a_ < mn) ? a_ : mn;                             \
        S = 0.25f * p1_ * sx_;                                \
    }

// one fp64 recurrence step (rare path; matches R2's refine bit-for-bit).
#define STEP64(xif, wd, Sd, o)                                \
    {                                                         \
        double xd_ = (double)(xif);                           \
        wd = 0.25 * xd_ + 0.75 * wd;                          \
        double arg_ = 0.5 - 0.5 * (0.25 * xd_ + wd);          \
        double p1_ = 1.0 / (1.0 + exp(-arg_));                \
        double pre_ = 0.25 * (xd_ + Sd) - 0.5;                \
        o = (pre_ > 0.0) ? 1.0f : 0.0f;                       \
        Sd = 0.25 * p1_ * (Sd + xd_);                         \
    }

// ws layout: ws[0] = count (zeroed per launch); ws[4..] = tid list
__global__ __launch_bounds__(256)
void pa_lif_fast(const float* __restrict__ x, float* __restrict__ out, int dim4,
                 unsigned* __restrict__ ws, unsigned capacity) {
    int tid = blockIdx.x * blockDim.x + threadIdx.x;
    if (tid >= dim4) return;

    const float4* __restrict__ xv = (const float4*)x;
    float4* __restrict__ ov = (float4*)out;
    vfloat4* __restrict__ onv = (vfloat4*)out;

    // stage all 8 rows up-front: 8 independent global_load_dwordx4 in flight
    // (R3 win: progressive vmcnt consumption instead of 8 serial round-trips)
    float4 xr[TT];
#pragma unroll
    for (int i = 0; i < TT; ++i)
        xr[i] = xv[(size_t)i * dim4 + tid];

    float w0 = 0.f, w1 = 0.f, w2 = 0.f, w3 = 0.f;
    float S0 = 0.f, S1 = 0.f, S2 = 0.f, S3 = 0.f;
    float mn = 1e30f;

    // compute + store immediately (no ot[] staging needed: stores are now
    // unconditional; boundary threads get overwritten by pass2, stream-ordered)
#pragma unroll
    for (int i = 0; i < TT; ++i) {
        vfloat4 o;
        STEP32(xr[i].x, w0, S0, o.x);
        STEP32(xr[i].y, w1, S1, o.y);
        STEP32(xr[i].z, w2, S2, o.z);
        STEP32(xr[i].w, w3, S3, o.w);
        __builtin_nontemporal_store(o, &onv[(size_t)i * dim4 + tid]);
    }

    bool need = (mn < REFINE_THRESH);
    unsigned long long mask = __ballot(need);   // uniform point: all lanes here
    if (need) {
        int lane = threadIdx.x & 63;
        int myidx = __popcll(mask & ((1ULL << lane) - 1ULL));
        if (capacity != 0u) {
            unsigned base = 0;
            if (myidx == 0)   // first set lane does the single per-wave atomic
                base = atomicAdd(ws, (unsigned)__popcll(mask));
            base = __builtin_amdgcn_readfirstlane(base);
            unsigned slot = base + (unsigned)myidx;
            if (slot < capacity) {
                ws[4 + slot] = (unsigned)tid;
                // pass2 will recompute + store this thread's outputs
            } else {
                // overflow fallback (not expected): inline fp64 refine.
                // Reload x from global with a rolled loop so xr[] keeps
                // compile-time-only indexing (stays in VGPRs, no scratch).
                double wd0 = 0, wd1 = 0, wd2 = 0, wd3 = 0;
                double Sd0 = 0, Sd1 = 0, Sd2 = 0, Sd3 = 0;
#pragma unroll 1
                for (int i = 0; i < TT; ++i) {
                    float4 xi = xv[(size_t)i * dim4 + tid];
                    float4 o;
                    STEP64(xi.x, wd0, Sd0, o.x);
                    STEP64(xi.y, wd1, Sd1, o.y);
                    STEP64(xi.z, wd2, Sd2, o.z);
                    STEP64(xi.w, wd3, Sd3, o.w);
                    ov[(size_t)i * dim4 + tid] = o;
                }
            }
        } else {
            // no workspace: inline fp64 refine (R3 behavior)
            double wd0 = 0, wd1 = 0, wd2 = 0, wd3 = 0;
            double Sd0 = 0, Sd1 = 0, Sd2 = 0, Sd3 = 0;
#pragma unroll 1
            for (int i = 0; i < TT; ++i) {
                float4 xi = xv[(size_t)i * dim4 + tid];
                float4 o;
                STEP64(xi.x, wd0, Sd0, o.x);
                STEP64(xi.y, wd1, Sd1, o.y);
                STEP64(xi.z, wd2, Sd2, o.z);
                STEP64(xi.w, wd3, Sd3, o.w);
                ov[(size_t)i * dim4 + tid] = o;
            }
        }
    }
}

// pass2: fp64 recompute of the compacted boundary threads only.
// Fixed grid (graph-capture safe); grid-strides over the runtime count.
__global__ __launch_bounds__(256)
void pa_lif_refine(const float* __restrict__ x, float* __restrict__ out, int dim4,
                   const unsigned* __restrict__ ws, unsigned capacity) {
    unsigned count = ws[0];
    if (count > capacity) count = capacity;  // overflowed entries were inlined
    const float4* __restrict__ xv = (const float4*)x;
    float4* __restrict__ ov = (float4*)out;
    unsigned stride = gridDim.x * blockDim.x;
    for (unsigned k = blockIdx.x * blockDim.x + threadIdx.x; k < count; k += stride) {
        int tid = (int)ws[4 + k];
        double wd0 = 0, wd1 = 0, wd2 = 0, wd3 = 0;
        double Sd0 = 0, Sd1 = 0, Sd2 = 0, Sd3 = 0;
#pragma unroll 1
        for (int i = 0; i < TT; ++i) {
            float4 xi = xv[(size_t)i * dim4 + tid];   // L2/L3-warm from pass1
            float4 o;
            STEP64(xi.x, wd0, Sd0, o.x);
            STEP64(xi.y, wd1, Sd1, o.y);
            STEP64(xi.z, wd2, Sd2, o.z);
            STEP64(xi.w, wd3, Sd3, o.w);
            ov[(size_t)i * dim4 + tid] = o;
        }
    }
}

extern "C" void kernel_launch(void* const* d_in, const int* in_sizes, int n_in,
                              void* d_out, int out_size, void* d_ws, size_t ws_size,
                              hipStream_t stream) {
    (void)n_in; (void)out_size;
    const float* x = (const float*)d_in[0];
    float* out = (float*)d_out;
    int total = in_sizes[0];        // T * dim = 16,777,216
    int dim = total / TT;           // 2,097,152 columns
    int dim4 = dim / 4;             // 524,288 threads (float4 per thread)
    int block = 256;
    int grid = (dim4 + block - 1) / block;

    // workspace: [0..15] counter block, [16..] tid list
    unsigned capacity = 0;
    unsigned* ws = (unsigned*)d_ws;
    if (ws != nullptr && ws_size >= 32) {
        size_t cap = (ws_size - 16) / 4;
        if (cap > (size_t)dim4) cap = (size_t)dim4;
        capacity = (unsigned)cap;
    }

    if (capacity != 0u) {
        hipMemsetAsync(d_ws, 0, 16, stream);   // stream-ordered, capturable
        pa_lif_fast<<<grid, block, 0, stream>>>(x, out, dim4, ws, capacity);
        pa_lif_refine<<<256, block, 0, stream>>>(x, out, dim4, ws, capacity);
    } else {
        pa_lif_fast<<<grid, block, 0, stream>>>(x, out, dim4, ws, 0u);
    }
}

// Round 3
// 106.662 us; speedup vs baseline: 1.0832x; 1.0832x over previous
//
#include <hip/hip_runtime.h>
#include <cmath>

// pa_lif: T=8, tau=0.25, thresh=0.5. Per-column recurrence (absmax 0.0 in R2):
//   w[i]   = 0.25*x[i] + 0.75*w[i-1]                      (W_CONST @ x as IIR)
//   p1[i]  = sigmoid(0.5 - 0.5*(0.25*x[i] + w[i]))
//   pre[i] = 0.25*(x[i] + S[i]) - 0.5 ;  out[i] = pre[i] > 0
//   S[i+1] = 0.25*p1[i]*(S[i] + x[i]) ;  S[0] = 0
//
// R5: back to the single-dispatch R1/R3 structure (two-pass compaction's 3
// stream-ordered dispatches cost more in launch/drain gaps than the fp64
// tax they removed: bench 110.4 -> 115.5). Instead the refining SET is
// shrunk: threshold 5e-5 was calibrated for the old precise-expf path; the
// fast path's |pre| error is <~3e-7 (1-ulp v_exp_f32, geometric contraction
// of S-errors by 0.25*p1 per step), so 5e-6 still has 15-20x margin.
//   refine rate: ~4%/thread -> ~0.4%/thread
//   P(wave has a refining lane): 93% -> ~23%
// Per-wave VALU: ~800 (fast) + 0.23*~4800 (fp64) ~= 1900 cy -> ~7 us total,
// overlappable under the ~16-18 us memory floor (R0 counters: FETCH 33.7 MB
// L3-assisted + WRITE 67.4 MB = 101 MB @ 6.3 TB/s).
// Threads moved off the fp64 path (mn in [5e-6, 5e-5)) have |pre| > 5e-6
// >> 3e-7 error -> fast sign == fp64 sign; still-refined threads get
// bit-identical fp64. Math of both paths unchanged from the verified R1.
//
// Determinism rule (round-1 lesson): every output address is written by
// EXACTLY ONE store site per launch — fast-store and refine-store are
// exclusive branches, no overwrites.

#define TT 8
#define REFINE_THRESH 5e-6f

// native vector type: __builtin_nontemporal_store requires a real vector,
// not HIP's float4 class
typedef float vfloat4 __attribute__((ext_vector_type(4)));

// one fast fp32 recurrence step for a single column (tracks min |pre| in `mn`)
// native exp2-based expf + hardware rcp; see error-margin note above.
#define STEP32(xik, w, S, o)                                  \
    {                                                         \
        float xk_ = (xik);                                    \
        w = fmaf(0.75f, w, 0.25f * xk_);                      \
        float arg_ = fmaf(-0.5f, fmaf(0.25f, xk_, w), 0.5f);  \
        float t_ = __expf(-arg_);                             \
        float p1_ = __builtin_amdgcn_rcpf(1.0f + t_);         \
        float sx_ = S + xk_;                                  \
        float pre_ = fmaf(0.25f, sx_, -0.5f);                 \
        o = (pre_ > 0.0f) ? 1.0f : 0.0f;                      \
        float a_ = fabsf(pre_);                               \
        mn = (a_ < mn) ? a_ : mn;                             \
        S = 0.25f * p1_ * sx_;                                \
    }

// one fp64 recurrence step (rare path; matches R2's refine bit-for-bit).
// Unique macro-local names: no shadowing of caller's variables.
#define STEP64(xif, wd, Sd, o)                                \
    {                                                         \
        double xd_ = (double)(xif);                           \
        wd = 0.25 * xd_ + 0.75 * wd;                          \
        double arg_ = 0.5 - 0.5 * (0.25 * xd_ + wd);          \
        double p1_ = 1.0 / (1.0 + exp(-arg_));                \
        double pre_ = 0.25 * (xd_ + Sd) - 0.5;                \
        o = (pre_ > 0.0) ? 1.0f : 0.0f;                       \
        Sd = 0.25 * p1_ * (Sd + xd_);                         \
    }

__global__ __launch_bounds__(256)
void pa_lif_kernel(const float* __restrict__ x, float* __restrict__ out, int dim4) {
    int tid = blockIdx.x * blockDim.x + threadIdx.x;
    if (tid >= dim4) return;

    const float4* __restrict__ xv = (const float4*)x;
    float4* __restrict__ ov = (float4*)out;
    vfloat4* __restrict__ onv = (vfloat4*)out;

    // stage all 8 rows up-front: 8 independent global_load_dwordx4 issue
    // back-to-back, consumed with progressive vmcnt waits (MLP = 128 B/thread)
    float4 xr[TT];
#pragma unroll
    for (int i = 0; i < TT; ++i)
        xr[i] = xv[(size_t)i * dim4 + tid];

    float4 ot[TT];
    float w0 = 0.f, w1 = 0.f, w2 = 0.f, w3 = 0.f;
    float S0 = 0.f, S1 = 0.f, S2 = 0.f, S3 = 0.f;
    float mn = 1e30f;

#pragma unroll
    for (int i = 0; i < TT; ++i) {
        STEP32(xr[i].x, w0, S0, ot[i].x);
        STEP32(xr[i].y, w1, S1, ot[i].y);
        STEP32(xr[i].z, w2, S2, ot[i].z);
        STEP32(xr[i].w, w3, S3, ot[i].w);
    }

    if (__builtin_expect(mn >= REFINE_THRESH, 1)) {
        // write-once stream: bypass L2 with nontemporal 16B stores
#pragma unroll
        for (int i = 0; i < TT; ++i) {
            vfloat4 o = {ot[i].x, ot[i].y, ot[i].z, ot[i].w};
            __builtin_nontemporal_store(o, &onv[(size_t)i * dim4 + tid]);
        }
    } else {
        // rare-lane fp64 recompute from the staged registers (no reloads).
        // Fully unrolled: xr[] indices stay compile-time constants so the
        // array lives in VGPRs, not scratch (runtime indexing would spill).
        double wd0 = 0, wd1 = 0, wd2 = 0, wd3 = 0;
        double Sd0 = 0, Sd1 = 0, Sd2 = 0, Sd3 = 0;
#pragma unroll
        for (int i = 0; i < TT; ++i) {
            float4 xi = xr[i];
            float4 o;
            STEP64(xi.x, wd0, Sd0, o.x);
            STEP64(xi.y, wd1, Sd1, o.y);
            STEP64(xi.z, wd2, Sd2, o.z);
            STEP64(xi.w, wd3, Sd3, o.w);
            ov[(size_t)i * dim4 + tid] = o;
        }
    }
}

extern "C" void kernel_launch(void* const* d_in, const int* in_sizes, int n_in,
                              void* d_out, int out_size, void* d_ws, size_t ws_size,
                              hipStream_t stream) {
    (void)n_in; (void)out_size; (void)d_ws; (void)ws_size;
    const float* x = (const float*)d_in[0];
    float* out = (float*)d_out;
    int total = in_sizes[0];        // T * dim = 16,777,216
    int dim = total / TT;           // 2,097,152 columns
    int dim4 = dim / 4;             // 524,288 threads (float4 per thread)
    int block = 256;
    int grid = (dim4 + block - 1) / block;
    pa_lif_kernel<<<grid, block, 0, stream>>>(x, out, dim4);
}